// Round 11
// baseline (74.919 us; speedup 1.0000x reference)
//
#include <hip/hip_runtime.h>

#define FD 128  // feature dim

typedef __attribute__((ext_vector_type(8))) short short8;   // 8 bf16
typedef __attribute__((ext_vector_type(4))) float f32x4;    // MFMA acc

__device__ __forceinline__ unsigned short f2bf(float f) {
    unsigned u = __float_as_uint(f);
    u += 0x7fff + ((u >> 16) & 1);   // round-to-nearest-even
    return (unsigned short)(u >> 16);
}
__device__ __forceinline__ float bf2f(unsigned short h) {
    return __uint_as_float(((unsigned)h) << 16);
}
// exact signed-int8 dot of 4 packed bytes
__device__ __forceinline__ int bdot4(unsigned x, unsigned y, int acc) {
#if __has_builtin(__builtin_amdgcn_sdot4)
    return __builtin_amdgcn_sdot4(x, y, acc, false);
#else
    acc += (((int)(x << 24)) >> 24) * (((int)(y << 24)) >> 24);
    acc += (((int)(x << 16)) >> 24) * (((int)(y << 16)) >> 24);
    acc += (((int)(x <<  8)) >> 24) * (((int)(y <<  8)) >> 24);
    acc += (((int)x) >> 24)         * (((int)y) >> 24);
    return acc;
#endif
}
__device__ __forceinline__ unsigned pack4f(float a, float b, float c, float d, float inv) {
    const int q0 = (int)rintf(a * inv), q1 = (int)rintf(b * inv);
    const int q2 = (int)rintf(c * inv), q3 = (int)rintf(d * inv);
    return (unsigned)(q0 & 255) | ((unsigned)(q1 & 255) << 8) |
           ((unsigned)(q2 & 255) << 16) | ((unsigned)(q3 & 255) << 24);
}

// ---------------------------------------------------------------------------
// Kernel 0: Wt[n][k] = bf16(W[k][n])  (128x128), short8 outputs.
// ---------------------------------------------------------------------------
__global__ void wt_kernel(const float* __restrict__ W, unsigned short* __restrict__ Wt) {
    const int tid = blockIdx.x * 256 + (int)threadIdx.x;   // 0..2047
    const int n  = tid & 127;
    const int k0 = (tid >> 7) * 8;
    short8 w;
    #pragma unroll
    for (int j = 0; j < 8; ++j) w[j] = (short)f2bf(W[(k0 + j) * FD + n]);
    *(short8*)(Wt + (size_t)n * FD + k0) = w;
}

// ---------------------------------------------------------------------------
// Kernel 1 (v6): fused u8 = int8rowquant(z @ W) AND z8 = int8rowquant(z).
// vs v5: NO Wt LDS staging and NO barriers. B-fragments are read directly
// from global Wt (32 KB, L1/L2-resident — identical values, bitwise-same
// output). The epilogue LDS region is per-wave PRIVATE (wave*8 KB), so
// waves run fully independently — global-load latency hides under other
// waves instead of stalling at block-wide syncs.
// Lane k-mapping contiguous (k0 = kq*32 + ks*8), verified v5.
// ---------------------------------------------------------------------------
__global__ __launch_bounds__(256)
void u_mfma6(const float* __restrict__ z, const unsigned short* __restrict__ Wt,
             unsigned char* __restrict__ u8, float* __restrict__ uscale,
             unsigned char* __restrict__ z8, float* __restrict__ zscale,
             int nrows) {
    __shared__ char eplds[32768];   // 4 waves x 8 KB private epilogue tiles
    const int tid  = (int)threadIdx.x;
    const int lane = tid & 63;
    const int wave = tid >> 6;
    const int l16  = lane & 15;
    const int kq   = lane >> 4;

    const long rowbase = (long)blockIdx.x * 64 + wave * 16;
    const long r  = rowbase + l16;
    const long rc = (r < nrows) ? r : (long)(nrows - 1);
    const bool rok = (r < nrows);

    f32x4 acc[8];
    #pragma unroll
    for (int nt = 0; nt < 8; ++nt)
        acc[nt] = (f32x4){0.f, 0.f, 0.f, 0.f};

    short8 avk[4];           // retained bf16 A-fragments (lane's 32 columns)
    float zmax = 1e-30f;     // abs-max of the SAME bf16 values we quantize

    #pragma unroll
    for (int ks = 0; ks < 4; ++ks) {
        const int k0 = kq * 32 + ks * 8;   // contiguous per-lane slice
        const float4* zp = (const float4*)(z + rc * FD + k0);
        const float4 f0 = zp[0];
        const float4 f1 = zp[1];
        short8 av;
        av[0] = (short)f2bf(f0.x); av[1] = (short)f2bf(f0.y);
        av[2] = (short)f2bf(f0.z); av[3] = (short)f2bf(f0.w);
        av[4] = (short)f2bf(f1.x); av[5] = (short)f2bf(f1.y);
        av[6] = (short)f2bf(f1.z); av[7] = (short)f2bf(f1.w);
        avk[ks] = av;
        #pragma unroll
        for (int j = 0; j < 8; ++j)
            zmax = fmaxf(zmax, fabsf(bf2f((unsigned short)av[j])));

        #pragma unroll
        for (int nt = 0; nt < 8; ++nt) {
            // B[k][n] fragment direct from global Wt (row-major [n][k]):
            // lane holds Wt[nt*16+l16][kq*32+ks*8 .. +7]
            const short8 b = *(const short8*)(
                Wt + (size_t)(nt * 16 + l16) * FD + kq * 32 + ks * 8);
            acc[nt] = __builtin_amdgcn_mfma_f32_16x16x32_bf16(av, b, acc[nt], 0, 0, 0);
        }
    }

    // z row-max across the 4 kq lanes of this row, then pack + store z8
    zmax = fmaxf(zmax, __shfl_xor(zmax, 16, 64));
    zmax = fmaxf(zmax, __shfl_xor(zmax, 32, 64));
    {
        const float inv = 127.0f / zmax;
        uint4 p0, p1;
        p0.x = pack4f(bf2f((unsigned short)avk[0][0]), bf2f((unsigned short)avk[0][1]),
                      bf2f((unsigned short)avk[0][2]), bf2f((unsigned short)avk[0][3]), inv);
        p0.y = pack4f(bf2f((unsigned short)avk[0][4]), bf2f((unsigned short)avk[0][5]),
                      bf2f((unsigned short)avk[0][6]), bf2f((unsigned short)avk[0][7]), inv);
        p0.z = pack4f(bf2f((unsigned short)avk[1][0]), bf2f((unsigned short)avk[1][1]),
                      bf2f((unsigned short)avk[1][2]), bf2f((unsigned short)avk[1][3]), inv);
        p0.w = pack4f(bf2f((unsigned short)avk[1][4]), bf2f((unsigned short)avk[1][5]),
                      bf2f((unsigned short)avk[1][6]), bf2f((unsigned short)avk[1][7]), inv);
        p1.x = pack4f(bf2f((unsigned short)avk[2][0]), bf2f((unsigned short)avk[2][1]),
                      bf2f((unsigned short)avk[2][2]), bf2f((unsigned short)avk[2][3]), inv);
        p1.y = pack4f(bf2f((unsigned short)avk[2][4]), bf2f((unsigned short)avk[2][5]),
                      bf2f((unsigned short)avk[2][6]), bf2f((unsigned short)avk[2][7]), inv);
        p1.z = pack4f(bf2f((unsigned short)avk[3][0]), bf2f((unsigned short)avk[3][1]),
                      bf2f((unsigned short)avk[3][2]), bf2f((unsigned short)avk[3][3]), inv);
        p1.w = pack4f(bf2f((unsigned short)avk[3][4]), bf2f((unsigned short)avk[3][5]),
                      bf2f((unsigned short)avk[3][6]), bf2f((unsigned short)avk[3][7]), inv);
        if (rok) {
            *(uint4*)(z8 + r * FD + kq * 32)      = p0;
            *(uint4*)(z8 + r * FD + kq * 32 + 16) = p1;
            if (kq == 0) zscale[r] = zmax * (1.0f / 127.0f);
        }
    }

    // fp32 repack in the wave's PRIVATE 8 KB region (no barrier needed;
    // within-wave ds_write->ds_read ordering handled by compiler lgkmcnt).
    char* wb = eplds + wave * 8192;
    #pragma unroll
    for (int nt = 0; nt < 8; ++nt) {
        const f32x4 v = acc[nt];
        #pragma unroll
        for (int rr = 0; rr < 4; ++rr) {
            const int row = kq * 4 + rr;            // 0..15
            const int cb4 = (nt * 16 + l16) * 4;    // byte col (f32)
            *(float*)(wb + row * 512 + (cb4 ^ ((row & 7) << 4))) = v[rr];
        }
    }
    #pragma unroll
    for (int i = 0; i < 8; ++i) {
        const int off = i * 1024 + lane * 16;   // 0..8191
        const int row = off >> 9;               // 0..15
        const int inr = off & 511;
        const float4 v = *(const float4*)(wb + (row << 9) + (inr ^ ((row & 7) << 4)));
        float m = fmaxf(fmaxf(fabsf(v.x), fabsf(v.y)), fmaxf(fabsf(v.z), fabsf(v.w)));
        #pragma unroll
        for (int offm = 1; offm < 32; offm <<= 1)
            m = fmaxf(m, __shfl_xor(m, offm, 64));
        m = fmaxf(m, 1e-30f);
        const float inv = 127.0f / m;
        const long grow = rowbase + row;
        if (grow < nrows) {
            *(unsigned*)(u8 + grow * FD + (inr >> 2)) = pack4f(v.x, v.y, v.z, v.w, inv);
            if ((lane & 31) == 0) uscale[grow] = m * (1.0f / 127.0f);
        }
    }
}

// ---------------------------------------------------------------------------
// Kernel 2 (v2): 3-stage pipelined int8 edge kernel.
// 8 lanes/edge, 16 B/lane; 8 edges/wave. Stage layout per iteration:
//   issue data gathers for e+S (indices loaded last iter — full iter slack),
//   issue index loads for e+2S,
//   compute e (data gathered last iter).
// Breaks the idx->gather dependency that serialized v1's prefetch.
// ---------------------------------------------------------------------------
__global__ __launch_bounds__(256)
void edge8p2(const unsigned char* __restrict__ u8, const unsigned char* __restrict__ z8,
             const float* __restrict__ uscale, const float* __restrict__ zscale,
             const int* __restrict__ src, const int* __restrict__ dst,
             const float* __restrict__ bias, float* __restrict__ out, int E) {
    const int tid  = (int)threadIdx.x;
    const int lane = tid & 63;
    const int sub  = lane >> 3;    // edge slot within wave (0..7)
    const int l8   = lane & 7;     // 16-B slice within the 128-B row
    const long wv  = (long)blockIdx.x * 4 + (tid >> 6);
    const long S   = (long)gridDim.x * 4 * 8;
    const float bv = bias[0];
    const long Em1 = (long)E - 1;

    long e = wv * 8 + sub;                     // < 65536 <= E always at entry
    // prologue: indices for e and e+S, data for e
    long ec  = (e     < E) ? e     : Em1;
    long ecn = (e + S < E) ? e + S : Em1;
    int s0 = src[ec],  t0 = dst[ec];
    int s1 = src[ecn], t1 = dst[ecn];
    uint4 xu0 = *((const uint4*)(u8 + (size_t)s0 * FD) + l8);
    uint4 xz0 = *((const uint4*)(z8 + (size_t)t0 * FD) + l8);
    float su0 = uscale[s0], sz0 = zscale[t0];

    while (e < E) {
        // stage B: data gathers for e+S (indices ready since last iter)
        const uint4 xu1 = *((const uint4*)(u8 + (size_t)s1 * FD) + l8);
        const uint4 xz1 = *((const uint4*)(z8 + (size_t)t1 * FD) + l8);
        const float su1 = uscale[s1], sz1 = zscale[t1];

        // stage A: index loads for e+2S
        const long e2  = e + 2 * S;
        const long e2c = (e2 < E) ? e2 : Em1;
        const int s2 = src[e2c], t2 = dst[e2c];

        // stage C: compute e
        int sum = 0;
        sum = bdot4(xu0.x, xz0.x, sum);
        sum = bdot4(xu0.y, xz0.y, sum);
        sum = bdot4(xu0.z, xz0.z, sum);
        sum = bdot4(xu0.w, xz0.w, sum);
        sum += __shfl_xor(sum, 4, 64);
        sum += __shfl_xor(sum, 2, 64);
        sum += __shfl_xor(sum, 1, 64);
        if (l8 == 0) out[e] = (float)sum * su0 * sz0 + bv;

        // rotate
        e += S;
        xu0 = xu1; xz0 = xz1; su0 = su1; sz0 = sz1;
        s1 = s2; t1 = t2;
    }
}

// ---------------------------------------------------------------------------
// Fallback (workspace too small): fused per-edge bilinear, fp32.
// ---------------------------------------------------------------------------
__global__ __launch_bounds__(128)
void bilinear_fused_fallback(const float* __restrict__ z, const float* __restrict__ Wg,
                             const int* __restrict__ src, const int* __restrict__ dst,
                             const float* __restrict__ bias, float* __restrict__ out,
                             int E) {
    __shared__ float Wl[FD * FD];
    __shared__ float zs[FD];
    __shared__ float red[2];
    for (int i = threadIdx.x; i < FD * FD; i += 128) Wl[i] = Wg[i];
    __syncthreads();
    const int j = (int)threadIdx.x;
    for (int e = blockIdx.x; e < E; e += gridDim.x) {
        const int s = src[e];
        const int t = dst[e];
        zs[j] = z[(size_t)s * FD + j];
        __syncthreads();
        float acc = 0.f;
        #pragma unroll 8
        for (int d = 0; d < FD; ++d) acc += zs[d] * Wl[d * FD + j];
        float p = acc * z[(size_t)t * FD + j];
        #pragma unroll
        for (int off = 32; off >= 1; off >>= 1)
            p += __shfl_xor(p, off, 64);
        if ((j & 63) == 0) red[j >> 6] = p;
        __syncthreads();
        if (j == 0) out[e] = red[0] + red[1] + bias[0];
        __syncthreads();
    }
}

extern "C" void kernel_launch(void* const* d_in, const int* in_sizes, int n_in,
                              void* d_out, int out_size, void* d_ws, size_t ws_size,
                              hipStream_t stream) {
    const float* z    = (const float*)d_in[0];
    const int*   ei   = (const int*)d_in[1];
    const float* W    = (const float*)d_in[2];
    const float* bias = (const float*)d_in[3];
    float* out = (float*)d_out;

    const int nrows = in_sizes[0] / FD;
    const int E     = in_sizes[1] / 2;
    const int* src = ei;
    const int* dst = ei + E;

    const size_t sz8 = (size_t)nrows * FD;                 // 12.8 MB int8 rows
    const size_t szs = (size_t)nrows * sizeof(float);      // 0.4 MB scales
    const size_t need = 2 * sz8 + 2 * szs + 256;

    if (ws_size >= need) {
        char* wsp = (char*)d_ws;
        unsigned char* u8  = (unsigned char*)wsp;
        unsigned char* z8  = (unsigned char*)(wsp + sz8);
        float* uscale = (float*)(wsp + 2 * sz8);
        float* zscale = (float*)(wsp + 2 * sz8 + szs);
        unsigned short* Wt = (unsigned short*)d_out;   // 32 KB staging; edge8p2
                                                       // overwrites all of d_out

        wt_kernel<<<8, 256, 0, stream>>>(W, Wt);
        const int nb1 = (nrows + 63) / 64;
        u_mfma6<<<nb1, 256, 0, stream>>>(z, Wt, u8, uscale, z8, zscale, nrows);
        edge8p2<<<2048, 256, 0, stream>>>(u8, z8, uscale, zscale, src, dst, bias, out, E);
    } else {
        bilinear_fused_fallback<<<2048, 128, 0, stream>>>(z, W, src, dst, bias, out, E);
    }
}

// Round 12
// 55.502 us; speedup vs baseline: 1.3498x; 1.3498x over previous
//
#include <hip/hip_runtime.h>

#define FD 128  // feature dim

typedef __attribute__((ext_vector_type(8))) short short8;   // 8 bf16
typedef __attribute__((ext_vector_type(4))) float f32x4;    // MFMA acc

__device__ __forceinline__ unsigned short f2bf(float f) {
    unsigned u = __float_as_uint(f);
    u += 0x7fff + ((u >> 16) & 1);   // round-to-nearest-even
    return (unsigned short)(u >> 16);
}
__device__ __forceinline__ float bf2f(unsigned short h) {
    return __uint_as_float(((unsigned)h) << 16);
}
// exact signed-int8 dot of 4 packed bytes
__device__ __forceinline__ int bdot4(unsigned x, unsigned y, int acc) {
#if __has_builtin(__builtin_amdgcn_sdot4)
    return __builtin_amdgcn_sdot4(x, y, acc, false);
#else
    acc += (((int)(x << 24)) >> 24) * (((int)(y << 24)) >> 24);
    acc += (((int)(x << 16)) >> 24) * (((int)(y << 16)) >> 24);
    acc += (((int)(x <<  8)) >> 24) * (((int)(y <<  8)) >> 24);
    acc += (((int)x) >> 24)         * (((int)y) >> 24);
    return acc;
#endif
}
__device__ __forceinline__ unsigned pack4f(float a, float b, float c, float d, float inv) {
    const int q0 = (int)rintf(a * inv), q1 = (int)rintf(b * inv);
    const int q2 = (int)rintf(c * inv), q3 = (int)rintf(d * inv);
    return (unsigned)(q0 & 255) | ((unsigned)(q1 & 255) << 8) |
           ((unsigned)(q2 & 255) << 16) | ((unsigned)(q3 & 255) << 24);
}

// ---------------------------------------------------------------------------
// Kernel 0: Wt[n][k] = bf16(W[k][n])  (128x128), short8 outputs.
// ---------------------------------------------------------------------------
__global__ void wt_kernel(const float* __restrict__ W, unsigned short* __restrict__ Wt) {
    const int tid = blockIdx.x * 256 + (int)threadIdx.x;   // 0..2047
    const int n  = tid & 127;
    const int k0 = (tid >> 7) * 8;
    short8 w;
    #pragma unroll
    for (int j = 0; j < 8; ++j) w[j] = (short)f2bf(W[(k0 + j) * FD + n]);
    *(short8*)(Wt + (size_t)n * FD + k0) = w;
}

// ---------------------------------------------------------------------------
// Kernel 1 (v7): fused u8 = int8rowquant(z @ W) AND z8 = int8rowquant(z).
// = v5 (LDS-staged Wt, verified in the 55.8-us round) + ONE change:
// the 8 z float4 loads are issued at the TOP of the kernel, before Wt
// staging, so their HBM latency drains under the staging + barrier.
// (Round-11 lesson: B-frags from global = latency chain at low occupancy;
// LDS staging is the right structure for the K-loop.)
// ---------------------------------------------------------------------------
__global__ __launch_bounds__(256)
void u_mfma7(const float* __restrict__ z, const unsigned short* __restrict__ Wt,
             unsigned char* __restrict__ u8, float* __restrict__ uscale,
             unsigned char* __restrict__ z8, float* __restrict__ zscale,
             int nrows) {
    __shared__ unsigned short Wl[FD * FD];  // 32 KB
    char* ldsb = (char*)Wl;
    const int tid  = (int)threadIdx.x;
    const int lane = tid & 63;
    const int wave = tid >> 6;
    const int l16  = lane & 15;
    const int kq   = lane >> 4;

    const long rowbase = (long)blockIdx.x * 64 + wave * 16;
    const long r  = rowbase + l16;
    const long rc = (r < nrows) ? r : (long)(nrows - 1);
    const bool rok = (r < nrows);

    // --- issue z loads FIRST (independent of staging; latency hides under
    // the Wt stage + barrier). 8 x float4 = lane's 32 contiguous columns.
    float4 zf[4][2];
    #pragma unroll
    for (int ks = 0; ks < 4; ++ks) {
        const float4* zp = (const float4*)(z + rc * FD + kq * 32 + ks * 8);
        zf[ks][0] = zp[0];
        zf[ks][1] = zp[1];
    }

    // stage Wt -> LDS, swizzled: byte = n*256 + (o ^ ((n&7)<<4))
    #pragma unroll
    for (int i = 0; i < 8; ++i) {
        const int c = i * 256 + tid;
        const int n = c >> 4;
        const int o = (c & 15) * 16;
        short8 v = *(const short8*)(Wt + (size_t)n * FD + (c & 15) * 8);
        *(short8*)(ldsb + n * 256 + (o ^ ((n & 7) << 4))) = v;
    }
    __syncthreads();

    f32x4 acc[8];
    #pragma unroll
    for (int nt = 0; nt < 8; ++nt)
        acc[nt] = (f32x4){0.f, 0.f, 0.f, 0.f};

    short8 avk[4];           // retained bf16 A-fragments (lane's 32 columns)
    float zmax = 1e-30f;     // abs-max of the SAME bf16 values we quantize

    #pragma unroll
    for (int ks = 0; ks < 4; ++ks) {
        const float4 f0 = zf[ks][0];
        const float4 f1 = zf[ks][1];
        short8 av;
        av[0] = (short)f2bf(f0.x); av[1] = (short)f2bf(f0.y);
        av[2] = (short)f2bf(f0.z); av[3] = (short)f2bf(f0.w);
        av[4] = (short)f2bf(f1.x); av[5] = (short)f2bf(f1.y);
        av[6] = (short)f2bf(f1.z); av[7] = (short)f2bf(f1.w);
        avk[ks] = av;
        #pragma unroll
        for (int j = 0; j < 8; ++j)
            zmax = fmaxf(zmax, fabsf(bf2f((unsigned short)av[j])));

        #pragma unroll
        for (int nt = 0; nt < 8; ++nt) {
            const int row = nt * 16 + l16;
            const short8 b = *(const short8*)(
                ldsb + row * 256 + ((kq * 64 + ks * 16) ^ ((row & 7) << 4)));
            acc[nt] = __builtin_amdgcn_mfma_f32_16x16x32_bf16(av, b, acc[nt], 0, 0, 0);
        }
    }

    // z row-max across the 4 kq lanes of this row, then pack + store z8
    zmax = fmaxf(zmax, __shfl_xor(zmax, 16, 64));
    zmax = fmaxf(zmax, __shfl_xor(zmax, 32, 64));
    {
        const float inv = 127.0f / zmax;
        uint4 p0, p1;
        p0.x = pack4f(bf2f((unsigned short)avk[0][0]), bf2f((unsigned short)avk[0][1]),
                      bf2f((unsigned short)avk[0][2]), bf2f((unsigned short)avk[0][3]), inv);
        p0.y = pack4f(bf2f((unsigned short)avk[0][4]), bf2f((unsigned short)avk[0][5]),
                      bf2f((unsigned short)avk[0][6]), bf2f((unsigned short)avk[0][7]), inv);
        p0.z = pack4f(bf2f((unsigned short)avk[1][0]), bf2f((unsigned short)avk[1][1]),
                      bf2f((unsigned short)avk[1][2]), bf2f((unsigned short)avk[1][3]), inv);
        p0.w = pack4f(bf2f((unsigned short)avk[1][4]), bf2f((unsigned short)avk[1][5]),
                      bf2f((unsigned short)avk[1][6]), bf2f((unsigned short)avk[1][7]), inv);
        p1.x = pack4f(bf2f((unsigned short)avk[2][0]), bf2f((unsigned short)avk[2][1]),
                      bf2f((unsigned short)avk[2][2]), bf2f((unsigned short)avk[2][3]), inv);
        p1.y = pack4f(bf2f((unsigned short)avk[2][4]), bf2f((unsigned short)avk[2][5]),
                      bf2f((unsigned short)avk[2][6]), bf2f((unsigned short)avk[2][7]), inv);
        p1.z = pack4f(bf2f((unsigned short)avk[3][0]), bf2f((unsigned short)avk[3][1]),
                      bf2f((unsigned short)avk[3][2]), bf2f((unsigned short)avk[3][3]), inv);
        p1.w = pack4f(bf2f((unsigned short)avk[3][4]), bf2f((unsigned short)avk[3][5]),
                      bf2f((unsigned short)avk[3][6]), bf2f((unsigned short)avk[3][7]), inv);
        if (rok) {
            *(uint4*)(z8 + r * FD + kq * 32)      = p0;
            *(uint4*)(z8 + r * FD + kq * 32 + 16) = p1;
            if (kq == 0) zscale[r] = zmax * (1.0f / 127.0f);
        }
    }

    __syncthreads();   // all waves done reading Wt; reuse LDS for epilogue

    // fp32 repack: wave's 16x128 f32 tile in its 8 KB region (verified v4/v5)
    char* wb = ldsb + wave * 8192;
    #pragma unroll
    for (int nt = 0; nt < 8; ++nt) {
        const f32x4 v = acc[nt];
        #pragma unroll
        for (int rr = 0; rr < 4; ++rr) {
            const int row = kq * 4 + rr;            // 0..15
            const int cb4 = (nt * 16 + l16) * 4;    // byte col (f32)
            *(float*)(wb + row * 512 + (cb4 ^ ((row & 7) << 4))) = v[rr];
        }
    }
    __syncthreads();

    #pragma unroll
    for (int i = 0; i < 8; ++i) {
        const int off = i * 1024 + lane * 16;   // 0..8191
        const int row = off >> 9;               // 0..15
        const int inr = off & 511;
        const float4 v = *(const float4*)(wb + (row << 9) + (inr ^ ((row & 7) << 4)));
        float m = fmaxf(fmaxf(fabsf(v.x), fabsf(v.y)), fmaxf(fabsf(v.z), fabsf(v.w)));
        #pragma unroll
        for (int offm = 1; offm < 32; offm <<= 1)
            m = fmaxf(m, __shfl_xor(m, offm, 64));
        m = fmaxf(m, 1e-30f);
        const float inv = 127.0f / m;
        const long grow = rowbase + row;
        if (grow < nrows) {
            *(unsigned*)(u8 + grow * FD + (inr >> 2)) = pack4f(v.x, v.y, v.z, v.w, inv);
            if ((lane & 31) == 0) uscale[grow] = m * (1.0f / 127.0f);
        }
    }
}

// ---------------------------------------------------------------------------
// Kernel 2 (v2): 3-stage pipelined int8 edge kernel. (Unchanged — measured
// ~26 us by subtraction in round 11; better than the 2-stage v1.)
// 8 lanes/edge, 16 B/lane; 8 edges/wave. Per iteration:
//   gather data for e+S (indices loaded last iter), load indices for e+2S,
//   compute e.
// ---------------------------------------------------------------------------
__global__ __launch_bounds__(256)
void edge8p2(const unsigned char* __restrict__ u8, const unsigned char* __restrict__ z8,
             const float* __restrict__ uscale, const float* __restrict__ zscale,
             const int* __restrict__ src, const int* __restrict__ dst,
             const float* __restrict__ bias, float* __restrict__ out, int E) {
    const int tid  = (int)threadIdx.x;
    const int lane = tid & 63;
    const int sub  = lane >> 3;    // edge slot within wave (0..7)
    const int l8   = lane & 7;     // 16-B slice within the 128-B row
    const long wv  = (long)blockIdx.x * 4 + (tid >> 6);
    const long S   = (long)gridDim.x * 4 * 8;
    const float bv = bias[0];
    const long Em1 = (long)E - 1;

    long e = wv * 8 + sub;
    long ec  = (e     < E) ? e     : Em1;
    long ecn = (e + S < E) ? e + S : Em1;
    int s0 = src[ec],  t0 = dst[ec];
    int s1 = src[ecn], t1 = dst[ecn];
    uint4 xu0 = *((const uint4*)(u8 + (size_t)s0 * FD) + l8);
    uint4 xz0 = *((const uint4*)(z8 + (size_t)t0 * FD) + l8);
    float su0 = uscale[s0], sz0 = zscale[t0];

    while (e < E) {
        const uint4 xu1 = *((const uint4*)(u8 + (size_t)s1 * FD) + l8);
        const uint4 xz1 = *((const uint4*)(z8 + (size_t)t1 * FD) + l8);
        const float su1 = uscale[s1], sz1 = zscale[t1];

        const long e2  = e + 2 * S;
        const long e2c = (e2 < E) ? e2 : Em1;
        const int s2 = src[e2c], t2 = dst[e2c];

        int sum = 0;
        sum = bdot4(xu0.x, xz0.x, sum);
        sum = bdot4(xu0.y, xz0.y, sum);
        sum = bdot4(xu0.z, xz0.z, sum);
        sum = bdot4(xu0.w, xz0.w, sum);
        sum += __shfl_xor(sum, 4, 64);
        sum += __shfl_xor(sum, 2, 64);
        sum += __shfl_xor(sum, 1, 64);
        if (l8 == 0) out[e] = (float)sum * su0 * sz0 + bv;

        e += S;
        xu0 = xu1; xz0 = xz1; su0 = su1; sz0 = sz1;
        s1 = s2; t1 = t2;
    }
}

// ---------------------------------------------------------------------------
// Fallback (workspace too small): fused per-edge bilinear, fp32.
// ---------------------------------------------------------------------------
__global__ __launch_bounds__(128)
void bilinear_fused_fallback(const float* __restrict__ z, const float* __restrict__ Wg,
                             const int* __restrict__ src, const int* __restrict__ dst,
                             const float* __restrict__ bias, float* __restrict__ out,
                             int E) {
    __shared__ float Wl[FD * FD];
    __shared__ float zs[FD];
    __shared__ float red[2];
    for (int i = threadIdx.x; i < FD * FD; i += 128) Wl[i] = Wg[i];
    __syncthreads();
    const int j = (int)threadIdx.x;
    for (int e = blockIdx.x; e < E; e += gridDim.x) {
        const int s = src[e];
        const int t = dst[e];
        zs[j] = z[(size_t)s * FD + j];
        __syncthreads();
        float acc = 0.f;
        #pragma unroll 8
        for (int d = 0; d < FD; ++d) acc += zs[d] * Wl[d * FD + j];
        float p = acc * z[(size_t)t * FD + j];
        #pragma unroll
        for (int off = 32; off >= 1; off >>= 1)
            p += __shfl_xor(p, off, 64);
        if ((j & 63) == 0) red[j >> 6] = p;
        __syncthreads();
        if (j == 0) out[e] = red[0] + red[1] + bias[0];
        __syncthreads();
    }
}

extern "C" void kernel_launch(void* const* d_in, const int* in_sizes, int n_in,
                              void* d_out, int out_size, void* d_ws, size_t ws_size,
                              hipStream_t stream) {
    const float* z    = (const float*)d_in[0];
    const int*   ei   = (const int*)d_in[1];
    const float* W    = (const float*)d_in[2];
    const float* bias = (const float*)d_in[3];
    float* out = (float*)d_out;

    const int nrows = in_sizes[0] / FD;
    const int E     = in_sizes[1] / 2;
    const int* src = ei;
    const int* dst = ei + E;

    const size_t sz8 = (size_t)nrows * FD;                 // 12.8 MB int8 rows
    const size_t szs = (size_t)nrows * sizeof(float);      // 0.4 MB scales
    const size_t need = 2 * sz8 + 2 * szs + 256;

    if (ws_size >= need) {
        char* wsp = (char*)d_ws;
        unsigned char* u8  = (unsigned char*)wsp;
        unsigned char* z8  = (unsigned char*)(wsp + sz8);
        float* uscale = (float*)(wsp + 2 * sz8);
        float* zscale = (float*)(wsp + 2 * sz8 + szs);
        unsigned short* Wt = (unsigned short*)d_out;   // 32 KB staging; edge8p2
                                                       // overwrites all of d_out

        wt_kernel<<<8, 256, 0, stream>>>(W, Wt);
        const int nb1 = (nrows + 63) / 64;
        u_mfma7<<<nb1, 256, 0, stream>>>(z, Wt, u8, uscale, z8, zscale, nrows);
        edge8p2<<<2048, 256, 0, stream>>>(u8, z8, uscale, zscale, src, dst, bias, out, E);
    } else {
        bilinear_fused_fallback<<<2048, 128, 0, stream>>>(z, W, src, dst, bias, out, E);
    }
}